// Round 7
// baseline (80.042 us; speedup 1.0000x reference)
//
#include <hip/hip_runtime.h>

#define NW 10

typedef float v2f __attribute__((ext_vector_type(2)));

// DPP: quad_perm xor1=0xB1, xor2=0x4E; row_ror:8 (xor8 within 16) = 0x128
template<int CTRL>
__device__ __forceinline__ float fdpp(float v) {
    return __int_as_float(__builtin_amdgcn_mov_dpp(__float_as_int(v), CTRL, 0xF, 0xF, true));
}
// ds_swizzle BitMode: xor4=0x101F, xor16=0x401F
template<int PAT>
__device__ __forceinline__ float fswz(float v) {
    return __int_as_float(__builtin_amdgcn_ds_swizzle(__float_as_int(v), PAT));
}

// ---- packed fp32 (VOP3P): one inst processes both components of a v2f ----
__device__ __forceinline__ v2f pkmul(v2f a, v2f b) {
    v2f d;
    asm("v_pk_mul_f32 %0, %1, %2" : "=v"(d) : "v"(a), "v"(b));
    return d;
}
__device__ __forceinline__ v2f pkfma(v2f a, v2f b, v2f c) {
    v2f d;
    asm("v_pk_fma_f32 %0, %1, %2, %3" : "=v"(d) : "v"(a), "v"(b), "v"(c));
    return d;
}
// complex mul r = a*b, a={re,im} coefficient, b={re,im} value, in 2 pk insts:
//   t = {a.x*b.x, a.x*b.y}          (src0 broadcasts word0 via op_sel_hi[0]=0)
//   r = {-a.y*b.y + t.x, a.y*b.x + t.y}
//       (src0 word1 both halves; src1 swapped: lo<-word1, hi<-word0; neg_lo on src0)
__device__ __forceinline__ v2f cmul(v2f a, v2f b) {
    v2f t, r;
    asm("v_pk_mul_f32 %0, %1, %2 op_sel_hi:[0,1]" : "=v"(t) : "v"(a), "v"(b));
    asm("v_pk_fma_f32 %0, %1, %2, %3 op_sel:[1,1,0] op_sel_hi:[1,0,1] neg_lo:[1,0,0]"
        : "=v"(r) : "v"(a), "v"(b), "v"(t));
    return r;
}

// ---------------- precompute: 7 folded diag tables (cs,sn) + 80 RY (cos,sin) ----
// (unchanged, verified) Fold rule: D2.P(D1.s)[u] = (D2[u]*D1[P(u)])*s[P(u)],
// P(s)=s^(s>>1)^((s&1)*0x300). Table index j: lane=j&63, r=(j>>6)&3, Wj=j>>8;
// entry is for position s = (Wj<<8)|(lane<<2)|r  (Wj bits = (x8,x9)).
__global__ void precompute_kernel(const float* __restrict__ params, float2* __restrict__ tab) {
    const int j = blockIdx.x * 256 + threadIdx.x;
    if (j < 7 * 1024) {
        const int d = j >> 10, jj = j & 1023;
        const int Wj = jj >> 8, lane = jj & 63, r = (jj >> 6) & 3;
        const int s = (Wj << 8) | (lane << 2) | r;
        const int q = s ^ (s >> 1) ^ ((s & 1) * 0x300);
        const float* thA;
        const float* thB;
        if (d < 4) {
            thA = params + (d * 6 + 3) * NW;          // rz3 of block d
            thB = params + (d * 6 + 2) * NW;          // rz2 of block d
        } else {
            const int k = d - 4;
            thA = params + ((k + 1) * 6 + 0) * NW;    // rz0 of block k+1
            thB = params + (k * 6 + 5) * NW;          // rz5 of block k
        }
        float ang = 0.f;
#pragma unroll
        for (int w = 0; w < NW; ++w) {
            ang += thA[w] * (((s >> (9 - w)) & 1) ? 0.5f : -0.5f);
            ang += thB[w] * (((q >> (9 - w)) & 1) ? 0.5f : -0.5f);
        }
        float sn, cs;
        __sincosf(ang, &sn, &cs);
        tab[j] = make_float2(cs, sn);
    } else if (j < 7 * 1024 + 80) {
        const int i = j - 7 * 1024;
        const int ry = i / NW, w = i % NW;
        const int k = ry >> 1, ii = ry & 1;
        const float* th = params + (k * 6 + (ii ? 4 : 1)) * NW;
        float sn, cs;
        __sincosf(0.5f * th[w], &sn, &cs);
        tab[7 * 1024 + i] = make_float2(cs, sn);
    }
}

// ---------------- main kernel: 2 waves = 1 sample, 8 amps/lane, packed math ----
// Element position s = x9..x0:
//   x0=u0 x1=u1 (reg bits) | x2..x7 = lane bits l0..l5 | x8=u2 (reg) | x9=WAVE bit W
// Wire w at position 9-w:
//   w9:u0 w8:u1 w7:l0(xor1 DPP) w6:l1(xor2 DPP) w5:l2(xor4 swz) w4:l3(xor8 DPP)
//   w3:l4(xor16 swz) w2:l5(xor32 shfl) w1:u2 | w0:WAVE (fused into LDS perm phase)
// Perm semantics: new[y] = old[P(y)], P(y)_i = y_i^y_{i+1} (i<8), P_8=y8^y9^y0, P_9=y9^y0.
// LDS idx(x) = ((x>>2)&63) | (x0<<6) | (x1<<7) | (x8<<8) | (x9<<9).
// Gather base(u=0): bits0..5 = pairwise lane XORs; bit7=l0; bit8=bit9=W.
// masks: u0->0x340, u1->0x0C0, u2->0x120 (XOR-closure table below).
// Fused w0 butterfly at src: val = c*A[si] + sw*A[si^0x200], src x9 = W ^ u0.

#define DPP_STAGE(CTRL, CW, BIT) do {                                          \
    const float2 cw_ = (CW);                                                   \
    const float ss_ = (lane & (BIT)) ? cw_.y : -cw_.y;                         \
    const v2f cv_ = {cw_.x, cw_.x}, sv_ = {ss_, ss_};                          \
    _Pragma("unroll")                                                          \
    for (int u_ = 0; u_ < 8; ++u_) {                                           \
        v2f p_;                                                                \
        p_.x = fdpp<CTRL>(st[u_].x);                                           \
        p_.y = fdpp<CTRL>(st[u_].y);                                           \
        st[u_] = pkfma(cv_, st[u_], pkmul(sv_, p_));                           \
    }                                                                          \
} while (0)

#define SWZ_STAGE(PAT, CW, BIT) do {                                           \
    const float2 cw_ = (CW);                                                   \
    const float ss_ = (lane & (BIT)) ? cw_.y : -cw_.y;                         \
    const v2f cv_ = {cw_.x, cw_.x}, sv_ = {ss_, ss_};                          \
    v2f p_[8];                                                                 \
    _Pragma("unroll")                                                          \
    for (int u_ = 0; u_ < 8; ++u_) {                                           \
        p_[u_].x = fswz<PAT>(st[u_].x);                                        \
        p_[u_].y = fswz<PAT>(st[u_].y);                                        \
    }                                                                          \
    _Pragma("unroll")                                                          \
    for (int u_ = 0; u_ < 8; ++u_) st[u_] = pkfma(cv_, st[u_], pkmul(sv_, p_[u_])); \
} while (0)

#define X32_STAGE(CW) do {                                                     \
    const float2 cw_ = (CW);                                                   \
    const float ss_ = (lane & 32) ? cw_.y : -cw_.y;                            \
    const v2f cv_ = {cw_.x, cw_.x}, sv_ = {ss_, ss_};                          \
    v2f p_[8];                                                                 \
    _Pragma("unroll")                                                          \
    for (int u_ = 0; u_ < 8; ++u_) {                                           \
        p_[u_].x = __shfl_xor(st[u_].x, 32, 64);                               \
        p_[u_].y = __shfl_xor(st[u_].y, 32, 64);                               \
    }                                                                          \
    _Pragma("unroll")                                                          \
    for (int u_ = 0; u_ < 8; ++u_) st[u_] = pkfma(cv_, st[u_], pkmul(sv_, p_[u_])); \
} while (0)

__global__ __launch_bounds__(128, 4) void qsim_kernel(const float* __restrict__ x,
                                                      const float2* __restrict__ tab,
                                                      float* __restrict__ out) {
    __shared__ v2f ex[2][1024];
    __shared__ float sred[2][NW];

    const int t    = threadIdx.x;
    const int W    = t >> 6;                 // wave bit = position x9 (wire 0)
    const int lane = t & 63;
    const int b    = blockIdx.x;             // one sample per 2-wave block
    const float2* ry_tab = tab + 7 * 1024;

    const int l0 = lane & 1, l1 = (lane >> 1) & 1, l2 = (lane >> 2) & 1,
              l3 = (lane >> 3) & 1, l4 = (lane >> 4) & 1, l5 = (lane >> 5) & 1;

    // ---- gather base (u=0), src = P(dest): pairwise XORs ----
    const int base = (l0 ^ l1) | ((l1 ^ l2) << 1) | ((l2 ^ l3) << 2)
                   | ((l3 ^ l4) << 3) | ((l4 ^ l5) << 4) | (l5 << 5)
                   | (l0 << 7) | (W << 8) | (W << 9);
    const int widx = lane | (W << 9);        // own write slot (idx space, +u<<6)

    v2f st[8];
    v2f xp[8];
    v2f tq[8];
    int bs = 0;

    // x-phase e^{iA_x(s)} per register
    {
        const float* xb = x + b * NW;
        float xv[NW];
#pragma unroll
        for (int w = 0; w < NW; ++w) xv[w] = xb[w];
        float A = 0.f;
#pragma unroll
        for (int w = 0; w < NW; ++w) A += xv[w];
        float hb = -0.5f * A;
        if (l0) hb += xv[7];
        if (l1) hb += xv[6];
        if (l2) hb += xv[5];
        if (l3) hb += xv[4];
        if (l4) hb += xv[3];
        if (l5) hb += xv[2];
        if (W)  hb += xv[0];
#pragma unroll
        for (int u = 0; u < 8; ++u) {
            float ang = hb;
            if (u & 1) ang += xv[9];
            if (u & 2) ang += xv[8];
            if (u & 4) ang += xv[1];
            float sn, cs;
            __sincosf(ang, &sn, &cs);
            xp[u] = (v2f){cs, sn};
        }
    }

    // prefetch folded-diag entries: tab[(d<<10) + lane + u0<<6 + u1<<7 + u2<<8 + W<<9]
    auto pre = [&](int d) {
        const v2f* tb = (const v2f*)(tab + (d << 10) + lane + (W << 9));
#pragma unroll
        for (int u = 0; u < 8; ++u)
            tq[u] = tb[((u & 3) << 6) | (((u >> 2) & 1) << 8)];
    };

    // analytic init: product state after full ry(0); wire0 factor from W
    auto initC = [&]() {
        const float2 r9 = ry_tab[9], r8 = ry_tab[8], r7 = ry_tab[7], r6 = ry_tab[6],
                     r5 = ry_tab[5], r4 = ry_tab[4], r3 = ry_tab[3], r2 = ry_tab[2],
                     r1 = ry_tab[1], r0 = ry_tab[0];
        float P6 = (l0 ? r7.y : r7.x) * (l1 ? r6.y : r6.x) * (l2 ? r5.y : r5.x)
                 * (l3 ? r4.y : r4.x) * (l4 ? r3.y : r3.x) * (l5 ? r2.y : r2.x);
        P6 *= (W ? r0.y : r0.x);
#pragma unroll
        for (int u = 0; u < 8; ++u) {
            float v = P6 * ((u & 1) ? r9.y : r9.x) * ((u & 2) ? r8.y : r8.x)
                         * ((u & 4) ? r1.y : r1.x);
            st[u] = (v2f){v, 0.f};
        }
    };

    // register-local butterfly on reg-bit m (packed)
    auto bflyL = [&](float2 cw, int m) {
        const v2f cv = {cw.x, cw.x}, sv = {cw.y, cw.y}, nv = {-cw.y, -cw.y};
#pragma unroll
        for (int u = 0; u < 8; ++u)
            if (!(u & m)) {
                const int v = u | m;
                const v2f a = st[u], bb = st[v];
                st[u] = pkfma(cv, a, pkmul(nv, bb));
                st[v] = pkfma(sv, a, pkmul(cv, bb));
            }
    };

    // 9 wave-local RY stages (w0 deferred to the fused LDS phase)
    auto ry = [&](int ridx) {
        const float2* rt = ry_tab + ridx * NW;
        bflyL(rt[9], 1);                 // w9: u0
        bflyL(rt[8], 2);                 // w8: u1
        bflyL(rt[1], 4);                 // w1: u2
        DPP_STAGE(0xB1, rt[7], 1);       // w7: l0 xor1
        DPP_STAGE(0x4E, rt[6], 2);       // w6: l1 xor2
        SWZ_STAGE(0x101F, rt[5], 4);     // w5: l2 xor4
        DPP_STAGE(0x128, rt[4], 8);      // w4: l3 xor8
        SWZ_STAGE(0x401F, rt[3], 16);    // w3: l4 xor16
        X32_STAGE(rt[2]);                // w2: l5 xor32
    };

    // fused: w0 butterfly (coeff cw0) + perm + diag (mode1 also x-phase)
    auto permFuse = [&](int mode, float2 cw0, bool withB) {
        v2f* B = ex[bs]; bs ^= 1;
#pragma unroll
        for (int u = 0; u < 8; ++u) B[widx + (u << 6)] = st[u];
        __syncthreads();
        const float sb = W ? cw0.y : -cw0.y;       // src x9 = W ^ u0
        const v2f c0v = {cw0.x, cw0.x};
        const v2f sbp = {sb, sb};
        const v2f sbn = {-sb, -sb};
        constexpr int msk[8] = {0x000, 0x340, 0x0C0, 0x380, 0x120, 0x260, 0x1E0, 0x2A0};
        v2f ns[8];
#pragma unroll
        for (int u = 0; u < 8; ++u) {
            const int si = base ^ msk[u];
            const v2f a = B[si];
            if (withB) {
                const v2f p = B[si ^ 0x200];
                ns[u] = pkfma(c0v, a, pkmul((u & 1) ? sbn : sbp, p));
            } else {
                ns[u] = a;
            }
        }
#pragma unroll
        for (int u = 0; u < 8; ++u) {
            v2f coef = tq[u];
            if (mode) coef = cmul(coef, xp[u]);
            st[u] = cmul(coef, ns[u]);
        }
    };

    // standalone w0 cross-wave butterfly (after ry(7), no perm follows)
    auto w0x = [&](float2 cw0) {
        v2f* B = ex[bs]; bs ^= 1;
#pragma unroll
        for (int u = 0; u < 8; ++u) B[widx + (u << 6)] = st[u];
        __syncthreads();
        const float sw = W ? cw0.y : -cw0.y;
        const v2f c0v = {cw0.x, cw0.x}, swv = {sw, sw};
#pragma unroll
        for (int u = 0; u < 8; ++u) {
            const v2f p = B[(widx ^ 0x200) + (u << 6)];
            st[u] = pkfma(c0v, st[u], pkmul(swv, p));
        }
    };

#pragma unroll 1
    for (int k = 0; k < 4; ++k) {
        pre(k);                                          // T1[k]
        if (k == 0) initC();
        else        ry(2 * k);
        permFuse(0, ry_tab[(2 * k) * NW], k != 0);       // w0(2k) + perm + rz2.P*rz3
        if (k < 3) pre(4 + k);                           // T2[k]
        ry(2 * k + 1);
        if (k < 3) permFuse(1, ry_tab[(2 * k + 1) * NW], true);  // w0 + perm + T2*enc
        else       w0x(ry_tab[7 * NW]);                  // k==3: bare w0 butterfly
        // k==3: rz5 pure phase (dropped); final perm folded into epilogue signs.
    }

    // ---- epilogue: out[w] = sum_e (-1)^{P^{-1}(e)_{9-w}} |st(e)|^2
    // e-bits: e0=u0 e1=u1 e2..e7=l0..l5 e8=u2 e9=W.
    // P^{-1}: x8=e8^e9; x_j = e_j^..^e7^e8^e9 (j<=7); x9 = e0^..^e8 (no e9).
    float pr[8];
#pragma unroll
    for (int u = 0; u < 8; ++u) pr[u] = st[u].x * st[u].x + st[u].y * st[u].y;

    float q0[2], q1[2], q2[2];
#pragma unroll
    for (int g = 0; g < 2; ++g) {
        const float a = pr[4 * g] + pr[4 * g + 1], bb = pr[4 * g + 2] + pr[4 * g + 3];
        const float c = pr[4 * g] - pr[4 * g + 1], d = pr[4 * g + 2] - pr[4 * g + 3];
        q0[g] = a + bb;   // sum over u0,u1
        q1[g] = a - bb;   // (-1)^{u1}
        q2[g] = c - d;    // (-1)^{u0^u1}
    }
    const float S0 = q0[0] - q0[1];          // (-1)^{u2}
    const float S1 = q1[0] - q1[1];          // (-1)^{u1^u2}
    const float S2 = q2[0] - q2[1];          // (-1)^{u0^u1^u2}
    const float sg = W ? -1.f : 1.f;         // (-1)^{e9}
    const float R23   = sg * S0;             // (-1)^{e8^e9}
    const float R123  = sg * S1;             // (-1)^{u1^u2^W}
    const float R0123 = sg * S2;             // (-1)^{u0^u1^u2^W}
    const float R012  = S2;                  // (-1)^{u0^u1^u2}

    // lane suffix parities over l5..l0 (= e7..e2)
    const int P5 = l5, P4 = l4 ^ P5, P3 = l3 ^ P4, P2 = l2 ^ P3, P1 = l1 ^ P2, P0 = l0 ^ P1;

    float acc[NW];
    acc[0] = P0 ? -R012 : R012;    // x9
    acc[1] = R23;                  // x8
    acc[2] = P5 ? -R23 : R23;      // x7
    acc[3] = P4 ? -R23 : R23;      // x6
    acc[4] = P3 ? -R23 : R23;      // x5
    acc[5] = P2 ? -R23 : R23;      // x4
    acc[6] = P1 ? -R23 : R23;      // x3
    acc[7] = P0 ? -R23 : R23;      // x2
    acc[8] = P0 ? -R123 : R123;    // x1
    acc[9] = P0 ? -R0123 : R0123;  // x0

#pragma unroll
    for (int w = 0; w < NW; ++w) {
        float a = acc[w];
        a += fdpp<0xB1>(a);
        a += fdpp<0x4E>(a);
        a += fswz<0x101F>(a);
        a += fdpp<0x128>(a);
        a += fswz<0x401F>(a);
        a += __shfl_xor(a, 32, 64);
        acc[w] = a;
    }
    if (lane == 0) {
#pragma unroll
        for (int w = 0; w < NW; ++w) sred[W][w] = acc[w];
    }
    __syncthreads();
    if (t < NW) out[b * NW + t] = sred[0][t] + sred[1][t];
}

extern "C" void kernel_launch(void* const* d_in, const int* in_sizes, int n_in,
                              void* d_out, int out_size, void* d_ws, size_t ws_size,
                              hipStream_t stream) {
    const float* x      = (const float*)d_in[0];   // (2048, 10)
    const float* params = (const float*)d_in[1];   // (4, 6, 10)
    float* out          = (float*)d_out;           // (1, 2048, 10)
    float2* tab         = (float2*)d_ws;           // 7*1024+80 float2 = 57 KB
    (void)in_sizes; (void)n_in; (void)out_size; (void)ws_size;
    precompute_kernel<<<29, 256, 0, stream>>>(params, tab);
    qsim_kernel<<<2048, 128, 0, stream>>>(x, tab, out);
}